// Round 7
// baseline (125.068 us; speedup 1.0000x reference)
//
#include <hip/hip_runtime.h>
#include <hip/hip_bf16.h>

typedef __bf16 bf16x8 __attribute__((ext_vector_type(8)));
typedef float f32x4 __attribute__((ext_vector_type(4)));
#define MFMA16 __builtin_amdgcn_mfma_f32_16x16x32_bf16

static constexpr int Bsz = 4, T = 4096, C = 1024, H = 128;
static constexpr int BT = Bsz * T; // 16384

__device__ __forceinline__ void gl2lds16(const __bf16* g, __bf16* l) {
    __builtin_amdgcn_global_load_lds(
        (const __attribute__((address_space(1))) void*)g,
        (__attribute__((address_space(3))) void*)l, 16, 0, 0);
}

// -------- kernel 0: W fp32[1024][128]x3 -> WTall bf16[384][1024] -----------
__global__ __launch_bounds__(256) void k_wprep(
    const float* __restrict__ Wq, const float* __restrict__ Wk,
    const float* __restrict__ Wv, __bf16* __restrict__ WTall)
{
    int idx = blockIdx.x * 256 + threadIdx.x;   // 0..393215
    int n = idx >> 10, k = idx & 1023;
    int mat = n >> 7, col = n & 127;
    const float* W = mat == 0 ? Wq : (mat == 1 ? Wk : Wv);
    float s = (mat == 1) ? 0.045084220f : 1.0f;  // 1/32 * log2(e)
    WTall[idx] = (__bf16)(W[k * H + col] * s);
}

// -------- kernel 1: QKV projection GEMM (unchanged, verified) --------------
__global__ __launch_bounds__(512) void k_proj(
    const float* __restrict__ X, const __bf16* __restrict__ WTall,
    __bf16* __restrict__ Qp, __bf16* __restrict__ Kp, __bf16* __restrict__ VT)
{
    union Smem {
        struct { __bf16 a[2][64 * 64]; __bf16 b[2][384 * 64]; } s; // 112KB
        __bf16 vt_e[128][72];
    };
    __shared__ Smem su;

    const int tid = threadIdx.x;
    const int lane = tid & 63, w = tid >> 6;
    const int c = lane & 15, hi = lane >> 4;
    const int wm = w >> 2, wn = w & 3;
    const int m0 = blockIdx.x * 64;
    const int xorv = (c & 7) << 3;

    const int arow = tid >> 3, ac8 = tid & 7;
    const float* aSrc = X + (size_t)(m0 + arow) * C + ac8 * 8;
    const int aDst = arow * 64 + ((ac8 * 8) ^ ((arow & 7) << 3));
    const int brl = lane >> 3, bch = lane & 7;

    f32x4 acc[2][6];
    #pragma unroll
    for (int i = 0; i < 2; ++i)
        #pragma unroll
        for (int j = 0; j < 6; ++j) acc[i][j] = (f32x4){0.f, 0.f, 0.f, 0.f};

    #pragma unroll
    for (int ib = 0; ib < 6; ++ib) {
        int row = w * 48 + ib * 8 + brl;
        int ch = bch ^ (row & 7);
        gl2lds16(WTall + (size_t)row * 1024 + ch * 8, &su.s.b[0][(w * 6 + ib) * 512]);
    }
    {
        float4 f0 = *(const float4*)aSrc;
        float4 f1 = *(const float4*)(aSrc + 4);
        bf16x8 av;
        av[0] = (__bf16)f0.x; av[1] = (__bf16)f0.y; av[2] = (__bf16)f0.z; av[3] = (__bf16)f0.w;
        av[4] = (__bf16)f1.x; av[5] = (__bf16)f1.y; av[6] = (__bf16)f1.z; av[7] = (__bf16)f1.w;
        *(bf16x8*)&su.s.a[0][aDst] = av;
    }
    __syncthreads();

    for (int t = 0; t < 16; ++t) {
        int cur = t & 1;
        float4 g0, g1;
        if (t < 15) {
            int k0 = (t + 1) * 64;
            #pragma unroll
            for (int ib = 0; ib < 6; ++ib) {
                int row = w * 48 + ib * 8 + brl;
                int ch = bch ^ (row & 7);
                gl2lds16(WTall + (size_t)row * 1024 + k0 + ch * 8,
                         &su.s.b[cur ^ 1][(w * 6 + ib) * 512]);
            }
            g0 = *(const float4*)(aSrc + k0);
            g1 = *(const float4*)(aSrc + k0 + 4);
        }
        #pragma unroll
        for (int kk = 0; kk < 2; ++kk) {
            bf16x8 a0 = *(const bf16x8*)&su.s.a[cur][(wm * 32 + c) * 64 + ((kk * 32 + hi * 8) ^ xorv)];
            bf16x8 a1 = *(const bf16x8*)&su.s.a[cur][(wm * 32 + 16 + c) * 64 + ((kk * 32 + hi * 8) ^ xorv)];
            #pragma unroll
            for (int fn = 0; fn < 6; ++fn) {
                bf16x8 bb = *(const bf16x8*)&su.s.b[cur][(wn * 96 + fn * 16 + c) * 64 + ((kk * 32 + hi * 8) ^ xorv)];
                acc[0][fn] = MFMA16(a0, bb, acc[0][fn], 0, 0, 0);
                acc[1][fn] = MFMA16(a1, bb, acc[1][fn], 0, 0, 0);
            }
        }
        if (t < 15) {
            bf16x8 av;
            av[0] = (__bf16)g0.x; av[1] = (__bf16)g0.y; av[2] = (__bf16)g0.z; av[3] = (__bf16)g0.w;
            av[4] = (__bf16)g1.x; av[5] = (__bf16)g1.y; av[6] = (__bf16)g1.z; av[7] = (__bf16)g1.w;
            *(bf16x8*)&su.s.a[cur ^ 1][aDst] = av;
        }
        __syncthreads();
    }

    #pragma unroll
    for (int mi = 0; mi < 2; ++mi) {
        int rowl = wm * 32 + mi * 16 + hi * 4;
        #pragma unroll
        for (int fn = 0; fn < 6; ++fn) {
            int nb = wn * 96 + fn * 16;
            int mat = nb >> 7, colb = (nb & 127) + c;
            #pragma unroll
            for (int r = 0; r < 4; ++r) {
                __bf16 v = (__bf16)acc[mi][fn][r];
                if (mat == 0)      Qp[(size_t)(m0 + rowl + r) * H + colb] = v;
                else if (mat == 1) Kp[(size_t)(m0 + rowl + r) * H + colb] = v;
                else               su.vt_e[colb][rowl + r] = v;
            }
        }
    }
    __syncthreads();
    {
        int d = tid >> 2, tc = (tid & 3) * 16;
        int b = m0 >> 12, tl = m0 & (T - 1);
        __bf16* dst = VT + ((size_t)b * H + d) * T + tl + tc;
        const __bf16* s2 = &su.vt_e[d][tc];
        *(uint4*)dst = *(const uint4*)s2;
        *(uint4*)(dst + 8) = *(const uint4*)(s2 + 8);
    }
}

// -------- kernel 2: causal attention, direct-from-L2, no in-loop barriers --
// 512 blocks x 256 thr. Block = (b, qt) 32-row q-tile, longest-first.
// 4 waves each own the SAME 32 rows and take s-steps i = w, w+4, ...
// Q/V read directly from global (L2-resident panels); P via per-wave LDS.
// Epilogue: merge 4 waves' partial O / row-sums in LDS, normalize, write.
__global__ __launch_bounds__(256, 2) void k_attn(
    const __bf16* __restrict__ Ka, const __bf16* __restrict__ Qb,
    const __bf16* __restrict__ VT, float* __restrict__ Out)
{
    __shared__ __bf16 pl[4][32][72];   // per-wave P tile, stride 144B (16B-aligned)
    __shared__ float oacc[32][132];
    __shared__ float sml[4][32];

    const int tid = threadIdx.x, lane = tid & 63, w = tid >> 6;
    const int c = lane & 15, hi = lane >> 4;

    const int bi = blockIdx.x;
    const int b = bi & 3, qt = 127 - (bi >> 2);   // longest-first
    const int t0 = qt * 32;
    const int nsteps = (qt >> 1) + 1;             // 64-wide s-steps

    const __bf16* Kb  = Ka + (size_t)b * T * H;
    const __bf16* Qbb = Qb + (size_t)b * T * H;
    const __bf16* Vb  = VT + (size_t)b * H * T;

    // A fragments: this wave's 32 K-rows (2 row-tiles), full H, in registers
    bf16x8 af[2][4];
    #pragma unroll
    for (int mi = 0; mi < 2; ++mi)
        #pragma unroll
        for (int kc = 0; kc < 4; ++kc)
            af[mi][kc] = *(const bf16x8*)(Kb + (size_t)(t0 + mi * 16 + c) * H + kc * 32 + hi * 8);

    f32x4 o[2][8], ol[2];
    #pragma unroll
    for (int mi = 0; mi < 2; ++mi) {
        #pragma unroll
        for (int nt = 0; nt < 8; ++nt) o[mi][nt] = (f32x4){0.f, 0.f, 0.f, 0.f};
        ol[mi] = (f32x4){0.f, 0.f, 0.f, 0.f};
    }
    bf16x8 ones;
    #pragma unroll
    for (int q8 = 0; q8 < 8; ++q8) ones[q8] = (__bf16)1.0f;

    for (int i = w; i < nsteps; i += 4) {
        const int s0 = i * 64;
        // QK^T: 32 rows x 64 s-cols, B-operand direct from L2
        f32x4 sa[2][4];
        #pragma unroll
        for (int mi = 0; mi < 2; ++mi)
            #pragma unroll
            for (int sc = 0; sc < 4; ++sc) sa[mi][sc] = (f32x4){0.f, 0.f, 0.f, 0.f};
        #pragma unroll
        for (int sc = 0; sc < 4; ++sc) {
            bf16x8 bq[4];
            #pragma unroll
            for (int kc = 0; kc < 4; ++kc)
                bq[kc] = *(const bf16x8*)(Qbb + (size_t)(s0 + sc * 16 + c) * H + kc * 32 + hi * 8);
            #pragma unroll
            for (int kc = 0; kc < 4; ++kc) {
                sa[0][sc] = MFMA16(af[0][kc], bq[kc], sa[0][sc], 0, 0, 0);
                sa[1][sc] = MFMA16(af[1][kc], bq[kc], sa[1][sc], 0, 0, 0);
            }
        }
        // exp2 + causal mask -> P in per-wave LDS
        const bool dz = (s0 + 63 >= t0);
        #pragma unroll
        for (int mi = 0; mi < 2; ++mi)
            #pragma unroll
            for (int sc = 0; sc < 4; ++sc)
                #pragma unroll
                for (int r = 0; r < 4; ++r) {
                    float e = __builtin_amdgcn_exp2f(sa[mi][sc][r]);
                    if (dz) {
                        int tg = t0 + mi * 16 + hi * 4 + r;
                        if (s0 + sc * 16 + c > tg) e = 0.f;
                    }
                    pl[w][mi * 16 + hi * 4 + r][sc * 16 + c] = (__bf16)e;
                }
        // PV: O[32][128] += P(32x64) @ V(64x128), V direct from L2
        #pragma unroll
        for (int ks = 0; ks < 2; ++ks) {
            bf16x8 pf0 = *(const bf16x8*)&pl[w][c][ks * 32 + hi * 8];
            bf16x8 pf1 = *(const bf16x8*)&pl[w][16 + c][ks * 32 + hi * 8];
            ol[0] = MFMA16(pf0, ones, ol[0], 0, 0, 0);
            ol[1] = MFMA16(pf1, ones, ol[1], 0, 0, 0);
            #pragma unroll
            for (int nt = 0; nt < 8; ++nt) {
                bf16x8 vb = *(const bf16x8*)(Vb + (size_t)(nt * 16 + c) * T + s0 + ks * 32 + hi * 8);
                o[0][nt] = MFMA16(pf0, vb, o[0][nt], 0, 0, 0);
                o[1][nt] = MFMA16(pf1, vb, o[1][nt], 0, 0, 0);
            }
        }
    }

    // ---- epilogue: merge 4 waves' partials, normalize, write fp32 ----
    if (c == 0) {
        #pragma unroll
        for (int mi = 0; mi < 2; ++mi)
            #pragma unroll
            for (int r = 0; r < 4; ++r)
                sml[w][mi * 16 + hi * 4 + r] = ol[mi][r];
    }
    __syncthreads();
    for (int wv = 0; wv < 4; ++wv) {
        if (w == wv) {
            #pragma unroll
            for (int mi = 0; mi < 2; ++mi)
                #pragma unroll
                for (int nt = 0; nt < 8; ++nt)
                    #pragma unroll
                    for (int r = 0; r < 4; ++r) {
                        int row = mi * 16 + hi * 4 + r, col = nt * 16 + c;
                        if (wv == 0) oacc[row][col]  = o[mi][nt][r];
                        else         oacc[row][col] += o[mi][nt][r];
                    }
        }
        __syncthreads();
    }
    {
        int row = tid >> 3, col0 = (tid & 7) * 16;
        float L = sml[0][row] + sml[1][row] + sml[2][row] + sml[3][row];
        float inv = 1.0f / L;
        float* dst = Out + ((size_t)b * T + t0 + row) * H + col0;
        #pragma unroll
        for (int q8 = 0; q8 < 16; q8 += 4) {
            float4 v;
            v.x = oacc[row][col0 + q8]     * inv;
            v.y = oacc[row][col0 + q8 + 1] * inv;
            v.z = oacc[row][col0 + q8 + 2] * inv;
            v.w = oacc[row][col0 + q8 + 3] * inv;
            *(float4*)(dst + q8) = v;
        }
    }
}

extern "C" void kernel_launch(void* const* d_in, const int* in_sizes, int n_in,
                              void* d_out, int out_size, void* d_ws, size_t ws_size,
                              hipStream_t stream) {
    const float* ix = (const float*)d_in[0];
    const float* Wq = (const float*)d_in[1];
    const float* Wk = (const float*)d_in[2];
    const float* Wv = (const float*)d_in[3];
    float* out = (float*)d_out;

    __bf16* WTall = (__bf16*)d_ws;                    // 384*1024
    __bf16* Qp = WTall + 393216;                      // [BT][H]
    __bf16* Kp = Qp + (size_t)BT * H;
    __bf16* VT = Kp + (size_t)BT * H;                 // [B][H][T]
    // total ws ~13.4 MB

    k_wprep<<<dim3(1536), 256, 0, stream>>>(Wq, Wk, Wv, WTall);
    k_proj<<<dim3(256), 512, 0, stream>>>(ix, WTall, Qp, Kp, VT);
    k_attn<<<dim3(512), 256, 0, stream>>>(Kp, Qp, VT, out);
}